// Round 7
// baseline (282.130 us; speedup 1.0000x reference)
//
#include <hip/hip_runtime.h>

// DynamicLinearModel, three-kernel split, round 7.
//
// theta_t = a*theta_{t-1} + c_{t-1},  a = sigmoid(G), c = Z@gamma, theta_0 = 0
// out_t   = theta_t + X_t@eta + Z_t@zeta
//
// Rounds 0-6 invariant: 256 MB of row-paired X/Z reads are served at
// ~2.5 TB/s regardless of occupancy (16-73%), staging mechanism (register
// pipeline, DPP, global_load_lds with 128 KB/CU outstanding), or trailing
// compute. Surviving theory: X[r] and Z[r] are exactly 128 MiB apart ->
// every paired load collides in L2 set, LLC set, and HBM channel phase;
// FETCH_SIZE stable at ~49% of demand matches halved-associativity LLC
// thrash on an LLC-sized footprint.
//
// This round splits the streams: zpass reads ONLY Z (c = Z@gamma -> ws,
// zb = Z@zeta -> out), xpass reads ONLY X (out += X@eta). Single-stream
// kernels, same proven DPP-reduce structure. Pass 2 (scan) unchanged.

#define WIN     64
#define CHUNK   256      // rows per block for zpass/xpass
#define P2C     256      // pass-2 rows per block
#define FCHUNK  256      // fallback fused kernel
#define RPI     64
#define NITER   ((WIN + FCHUNK) / RPI)

// ---- DPP 16-lane row sum: result in lane 15 of each 16-lane row ----------
template <int N>
__device__ __forceinline__ float rshr_add(float v) {
    const int s = __builtin_amdgcn_update_dpp(
        0, __float_as_int(v), 0x110 | N /*row_shr:N*/, 0xF, 0xF, true);
    return v + __int_as_float(s);
}
__device__ __forceinline__ float rsum16(float v) {
    v = rshr_add<8>(v);
    v = rshr_add<4>(v);
    v = rshr_add<2>(v);
    v = rshr_add<1>(v);
    return v;   // lane 15 of each row holds sum of all 16 lanes
}

// ---------------------------------------------------------------------------
// zpass: single-stream over Z. c[t]=Z[t].gamma -> ws; out[t]=Z[t].zeta.
// 16 lanes per row (1 KB coalesced wave-loads), A/B double-buffered bursts.
// ---------------------------------------------------------------------------
__global__ __launch_bounds__(256) void dlm_zpass(
    const float* __restrict__ Z,
    const float* __restrict__ zeta, const float* __restrict__ gam,
    float* __restrict__ c_ws, float* __restrict__ out, int T)
{
    const int tid  = threadIdx.x;
    const int lane = tid & 63;
    const int wv   = tid >> 6;        // wave 0..3
    const int sub  = lane & 15;       // float4 index within a 64-float row
    const int rsub = lane >> 4;       // row within the 4-row group
    const int s    = (int)blockIdx.x * CHUNK;
    const int Tm1  = T - 1;

    const float4 sz4 = ((const float4*)zeta)[sub];
    const float4 g4  = ((const float4*)gam)[sub];
    const float4* Z4 = (const float4*)Z;

    float4 A[4], B[4];

    auto issue = [&](float4 (&buf)[4], int i) {
        const int rb = s + i * 64 + wv * 16;
        #pragma unroll
        for (int u = 0; u < 4; ++u) {
            const int r = min(rb + u * 4 + rsub, Tm1);
            buf[u] = Z4[(size_t)r * 16 + sub];
        }
    };

    auto reduce_store = [&](const float4 (&buf)[4], int i) {
        float cp[4], zp[4];
        #pragma unroll
        for (int u = 0; u < 4; ++u) {
            const float4 z = buf[u];
            cp[u] = z.x*g4.x + z.y*g4.y + z.z*g4.z + z.w*g4.w;
            zp[u] = z.x*sz4.x + z.y*sz4.y + z.z*sz4.z + z.w*sz4.w;
            cp[u] = rsum16(cp[u]);
            zp[u] = rsum16(zp[u]);
        }
        if (sub == 15) {
            #pragma unroll
            for (int u = 0; u < 4; ++u) {
                const int t = s + i * 64 + wv * 16 + u * 4 + rsub;
                if (t < T) { c_ws[t] = cp[u]; out[t] = zp[u]; }
            }
        }
    };

    issue(A, 0);
    issue(B, 1);
    reduce_store(A, 0);
    issue(A, 2);
    reduce_store(B, 1);
    issue(B, 3);
    reduce_store(A, 2);
    reduce_store(B, 3);
}

// ---------------------------------------------------------------------------
// xpass: single-stream over X. out[t] += X[t].eta.
// ---------------------------------------------------------------------------
__global__ __launch_bounds__(256) void dlm_xpass(
    const float* __restrict__ X, const float* __restrict__ eta,
    float* __restrict__ out, int T)
{
    const int tid  = threadIdx.x;
    const int lane = tid & 63;
    const int wv   = tid >> 6;
    const int sub  = lane & 15;
    const int rsub = lane >> 4;
    const int s    = (int)blockIdx.x * CHUNK;
    const int Tm1  = T - 1;

    const float4 e4  = ((const float4*)eta)[sub];
    const float4* X4 = (const float4*)X;

    float4 A[4], B[4];

    auto issue = [&](float4 (&buf)[4], int i) {
        const int rb = s + i * 64 + wv * 16;
        #pragma unroll
        for (int u = 0; u < 4; ++u) {
            const int r = min(rb + u * 4 + rsub, Tm1);
            buf[u] = X4[(size_t)r * 16 + sub];
        }
    };

    auto reduce_store = [&](const float4 (&buf)[4], int i) {
        float xp[4];
        #pragma unroll
        for (int u = 0; u < 4; ++u) {
            const float4 x = buf[u];
            xp[u] = x.x*e4.x + x.y*e4.y + x.z*e4.z + x.w*e4.w;
            xp[u] = rsum16(xp[u]);
        }
        if (sub == 15) {
            #pragma unroll
            for (int u = 0; u < 4; ++u) {
                const int t = s + i * 64 + wv * 16 + u * 4 + rsub;
                if (t < T) out[t] += xp[u];
            }
        }
    };

    issue(A, 0);
    issue(B, 1);
    reduce_store(A, 0);
    issue(A, 2);
    reduce_store(B, 1);
    issue(B, 3);
    reduce_store(A, 2);
    reduce_store(B, 3);
}

// ---------------------------------------------------------------------------
// Pass 2: per-block scan over materialized c (hot in L2/L3 from zpass).
// ---------------------------------------------------------------------------
__global__ __launch_bounds__(256) void dlm_pass2(
    const float* __restrict__ c, const float* __restrict__ Gp,
    float* __restrict__ out, int T)
{
    const int tid = threadIdx.x;
    const int s   = (int)blockIdx.x * P2C;
    const int t   = s + tid;

    __shared__ float sc[P2C];
    __shared__ float theta_sh;

    const float g   = *Gp;
    const float a   = 1.0f / (1.0f + expf(-g));
    const float l2a = log2f(a);

    // v_t = c[t-1], v_0 = 0; b read up front (own element only, no hazard)
    const float v = (t >= 1 && t < T) ? c[t - 1] : 0.0f;
    const float b = (t < T) ? out[t] : 0.0f;

    // incoming state: theta_{s-1} = sum_{j=0..WIN-2} a^j * c[s-2-j]
    if (tid < 64) {
        float term = 0.0f;
        const int idx = s - 2 - tid;
        if (tid <= WIN - 2 && idx >= 0)
            term = exp2f((float)tid * l2a) * c[idx];
        #pragma unroll
        for (int off = 1; off <= 32; off <<= 1)
            term += __shfl_xor(term, off, 64);
        if (tid == 0) theta_sh = term;
    }

    sc[tid] = v;
    __syncthreads();
    const float theta_in = theta_sh;

    // inclusive Hillis-Steele scan, ratio a (squares each step)
    float Ad = a;
    for (int d = 1; d < P2C; d <<= 1) {
        const float self = sc[tid];
        const float prev = (tid >= d) ? sc[tid - d] : 0.0f;
        __syncthreads();
        sc[tid] = self + Ad * prev;
        __syncthreads();
        Ad *= Ad;
    }

    const float E = (tid > 0) ? sc[tid - 1] : 0.0f;
    float theta = exp2f((float)tid * l2a) * theta_in + E;
    theta = a * theta + v;
    if (t < T) out[t] = b + theta;
}

// ---------------------------------------------------------------------------
// Fallback: round-1 fused kernel (used only if workspace is too small).
// ---------------------------------------------------------------------------
__global__ __launch_bounds__(256) void dlm_fused(
    const float* __restrict__ X, const float* __restrict__ Z,
    const float* __restrict__ Gp,
    const float* __restrict__ eta, const float* __restrict__ zeta,
    const float* __restrict__ gam,
    float* __restrict__ out, int T)
{
    const int tid  = threadIdx.x;
    const int lane = tid & 63;
    const int wv   = tid >> 6;
    const int sub  = lane & 15;
    const int rsub = lane >> 4;
    const int s    = (int)blockIdx.x * FCHUNK;

    __shared__ float cl[WIN + FCHUNK];
    __shared__ float bl[FCHUNK];
    __shared__ float sc[256];
    __shared__ float theta_sh;

    const float4 e4  = ((const float4*)eta)[sub];
    const float4 sz4 = ((const float4*)zeta)[sub];
    const float4 g4  = ((const float4*)gam)[sub];
    const float4* X4 = (const float4*)X;
    const float4* Z4 = (const float4*)Z;

    const float g   = *Gp;
    const float a   = 1.0f / (1.0f + expf(-g));
    const float l2a = log2f(a);

    for (int i = 0; i < NITER; ++i) {
        const int rb = s - WIN + i * RPI + wv * 16;
        float cp[4], bp[4];
        #pragma unroll
        for (int u = 0; u < 4; ++u) {
            const int r = rb + u * 4 + rsub;
            float4 z = make_float4(0.f, 0.f, 0.f, 0.f);
            float4 x = make_float4(0.f, 0.f, 0.f, 0.f);
            const bool in = (r >= 0) && (r < T);
            if (in)           z = Z4[(size_t)r * 16 + sub];
            if (in && i > 0)  x = X4[(size_t)r * 16 + sub];
            cp[u] = z.x*g4.x + z.y*g4.y + z.z*g4.z + z.w*g4.w;
            bp[u] = x.x*e4.x + x.y*e4.y + x.z*e4.z + x.w*e4.w
                  + z.x*sz4.x + z.y*sz4.y + z.z*sz4.z + z.w*sz4.w;
        }
        #pragma unroll
        for (int u = 0; u < 4; ++u) {
            #pragma unroll
            for (int off = 1; off <= 8; off <<= 1) {
                cp[u] += __shfl_xor(cp[u], off, 64);
                bp[u] += __shfl_xor(bp[u], off, 64);
            }
        }
        if (sub == 0) {
            #pragma unroll
            for (int u = 0; u < 4; ++u) {
                const int r = rb + u * 4 + rsub;
                cl[r - s + WIN] = cp[u];
                if (i > 0) bl[r - s] = bp[u];
            }
        }
    }
    __syncthreads();

    if (tid < 64) {
        float term = 0.0f;
        if (tid <= WIN - 2)
            term = exp2f((float)tid * l2a) * cl[WIN - 2 - tid];
        #pragma unroll
        for (int off = 1; off <= 32; off <<= 1)
            term += __shfl_xor(term, off, 64);
        if (tid == 0) theta_sh = term;
    }

    const int t = s + tid;
    const float v = (t == 0) ? 0.0f : cl[WIN + tid - 1];
    sc[tid] = v;
    __syncthreads();
    const float theta_in = theta_sh;

    float Ad = a;
    for (int d = 1; d < 256; d <<= 1) {
        const float self = sc[tid];
        const float prev = (tid >= d) ? sc[tid - d] : 0.0f;
        __syncthreads();
        sc[tid] = self + Ad * prev;
        __syncthreads();
        Ad *= Ad;
    }

    const float E = (tid > 0) ? sc[tid - 1] : 0.0f;
    float theta = exp2f((float)tid * l2a) * theta_in + E;
    theta = a * theta + v;
    if (t < T) out[t] = bl[tid] + theta;
}

extern "C" void kernel_launch(void* const* d_in, const int* in_sizes, int n_in,
                              void* d_out, int out_size, void* d_ws, size_t ws_size,
                              hipStream_t stream) {
    const float* X     = (const float*)d_in[0];
    const float* Z     = (const float*)d_in[1];
    const float* G     = (const float*)d_in[2];
    const float* eta   = (const float*)d_in[3];
    const float* zeta  = (const float*)d_in[4];
    const float* gamma = (const float*)d_in[5];
    float* out = (float*)d_out;

    const int T = in_sizes[0] / 64;

    if (ws_size >= (size_t)T * sizeof(float)) {
        float* c_ws = (float*)d_ws;
        const int nb  = (T + CHUNK - 1) / CHUNK;
        const int nb2 = (T + P2C - 1) / P2C;
        dlm_zpass<<<nb, 256, 0, stream>>>(Z, zeta, gamma, c_ws, out, T);
        dlm_xpass<<<nb, 256, 0, stream>>>(X, eta, out, T);
        dlm_pass2<<<nb2, 256, 0, stream>>>(c_ws, G, out, T);
    } else {
        const int nbf = (T + FCHUNK - 1) / FCHUNK;
        dlm_fused<<<nbf, 256, 0, stream>>>(X, Z, G, eta, zeta, gamma, out, T);
    }
}